// Round 1
// baseline (228.536 us; speedup 1.0000x reference)
//
#include <hip/hip_runtime.h>

typedef unsigned short u16;
typedef float floatx4 __attribute__((ext_vector_type(4)));
typedef short shortx8 __attribute__((ext_vector_type(8)));

__device__ inline u16 f2bf(float f) {
  unsigned u = __float_as_uint(f);
  u += 0x7fffu + ((u >> 16) & 1u);
  return (u16)(u >> 16);
}
__device__ inline float bflo(unsigned u) { return __uint_as_float(u << 16); }
__device__ inline float bfhi(unsigned u) { return __uint_as_float(u & 0xffff0000u); }

// ---------------------------------------------------------------------------
// fp32 -> bf16 conversion of all tensors (w2_* zero-padded to 128/256 rows)
// region table (element offsets into the ushort base of d_ws):
//  qb 0..4194304, vb ..8388608, w1b0 ..8650752, w1b1 ..8912896,
//  w3b0 ..9175040, w3b1 ..9437184, wob ..9699328, w2b0p(128x512) ..9764864,
//  w2b1p(256x512) ..9895936
// ---------------------------------------------------------------------------
__global__ __launch_bounds__(256) void convert_all(
    const float* __restrict__ q, const float* __restrict__ v,
    const float* __restrict__ w10, const float* __restrict__ w11,
    const float* __restrict__ w30, const float* __restrict__ w31,
    const float* __restrict__ wo, const float* __restrict__ w20,
    const float* __restrict__ w21, u16* __restrict__ base) {
  size_t e = ((size_t)blockIdx.x * 256 + threadIdx.x) * 4;
  const float* src;
  u16* dst;
  size_t le;
  unsigned prows;
  if (e < 4194304ull)      { src = q;   dst = base;            le = e;            prows = 0x7fffffffu; }
  else if (e < 8388608ull) { src = v;   dst = base + 4194304;  le = e - 4194304;  prows = 0x7fffffffu; }
  else if (e < 8650752ull) { src = w10; dst = base + 8388608;  le = e - 8388608;  prows = 0x7fffffffu; }
  else if (e < 8912896ull) { src = w11; dst = base + 8650752;  le = e - 8650752;  prows = 0x7fffffffu; }
  else if (e < 9175040ull) { src = w30; dst = base + 8912896;  le = e - 8912896;  prows = 0x7fffffffu; }
  else if (e < 9437184ull) { src = w31; dst = base + 9175040;  le = e - 9175040;  prows = 0x7fffffffu; }
  else if (e < 9699328ull) { src = wo;  dst = base + 9437184;  le = e - 9437184;  prows = 0x7fffffffu; }
  else if (e < 9764864ull) { src = w20; dst = base + 9699328;  le = e - 9699328;  prows = 124; }
  else                     { src = w21; dst = base + 9764864;  le = e - 9764864;  prows = 244; }
  float4 val = make_float4(0.f, 0.f, 0.f, 0.f);
  if ((unsigned)(le >> 9) < prows) val = *(const float4*)(src + le);
  unsigned p0 = (unsigned)f2bf(val.x) | ((unsigned)f2bf(val.y) << 16);
  unsigned p1 = (unsigned)f2bf(val.z) | ((unsigned)f2bf(val.w) << 16);
  *(uint2*)(dst + le) = make_uint2(p0, p1);
}

// ---------------------------------------------------------------------------
// C[m,n] = sum_k A[m,k]*W[n,k], A:[M,512] bf16, W:[N,512] bf16.
// 128x128 tile, BK=32, 4 waves (2x2 of 64x64), mfma_f32_16x16x32_bf16.
// LDS row stride 40 ushorts: 16B-aligned b128 frag reads, 2-way banks (free).
// OUTBF: 1 -> bf16 out, 0 -> fp32 out.  RELU applied pre-store.
// ---------------------------------------------------------------------------
#define LDK 40

template <int OUTBF, int RELU>
__global__ __launch_bounds__(256, 2) void gemm_bt(
    const u16* __restrict__ A, const u16* __restrict__ W,
    float* __restrict__ Cf, u16* __restrict__ Cb, int N) {
  __shared__ __align__(16) u16 lA[128 * LDK];
  __shared__ __align__(16) u16 lB[128 * LDK];
  const int tid = threadIdx.x;
  const int bm = blockIdx.x * 128, bn = blockIdx.y * 128;
  const int wave = tid >> 6, lane = tid & 63;
  const int wm = (wave >> 1) * 64, wn = (wave & 1) * 64;
  const int lr = lane & 15, kq = (lane >> 4) * 8;
  floatx4 acc[4][4];
#pragma unroll
  for (int i = 0; i < 4; ++i)
#pragma unroll
    for (int j = 0; j < 4; ++j) acc[i][j] = (floatx4){0.f, 0.f, 0.f, 0.f};

  const int row0 = tid >> 2, col0 = (tid & 3) * 8;
  const int row1 = row0 + 64;
  for (int k0 = 0; k0 < 512; k0 += 32) {
    __syncthreads();
    *(uint4*)&lA[row0 * LDK + col0] = *(const uint4*)&A[(size_t)(bm + row0) * 512 + k0 + col0];
    *(uint4*)&lB[row0 * LDK + col0] = *(const uint4*)&W[(size_t)(bn + row0) * 512 + k0 + col0];
    *(uint4*)&lA[row1 * LDK + col0] = *(const uint4*)&A[(size_t)(bm + row1) * 512 + k0 + col0];
    *(uint4*)&lB[row1 * LDK + col0] = *(const uint4*)&W[(size_t)(bn + row1) * 512 + k0 + col0];
    __syncthreads();
    shortx8 af[4], bf8[4];
#pragma unroll
    for (int i = 0; i < 4; ++i) {
      af[i] = *(const shortx8*)&lA[(wm + i * 16 + lr) * LDK + kq];
      bf8[i] = *(const shortx8*)&lB[(wn + i * 16 + lr) * LDK + kq];
    }
#pragma unroll
    for (int mi = 0; mi < 4; ++mi)
#pragma unroll
      for (int ni = 0; ni < 4; ++ni)
        acc[mi][ni] = __builtin_amdgcn_mfma_f32_16x16x32_bf16(af[mi], bf8[ni], acc[mi][ni], 0, 0, 0);
  }
  // C/D layout: col = lane&15, row = (lane>>4)*4 + r   (verified m89/m91)
  const int rb0 = bm + wm + (lane >> 4) * 4;
  const int cb0 = bn + wn + (lane & 15);
#pragma unroll
  for (int mi = 0; mi < 4; ++mi)
#pragma unroll
    for (int ni = 0; ni < 4; ++ni)
#pragma unroll
      for (int r = 0; r < 4; ++r) {
        float vv = acc[mi][ni][r];
        if (RELU) vv = fmaxf(vv, 0.f);
        size_t off = (size_t)(rb0 + mi * 16 + r) * (size_t)N + (size_t)(cb0 + ni * 16);
        if (OUTBF) Cb[off] = f2bf(vv);
        else Cf[off] = vv;
      }
}

// ---------------------------------------------------------------------------
// Fused softmax + banded attn for one scale.
// Block = (t-tile of 64, head h, batch b). 256 threads.
// es[tt][r] = exp(logit[tt][r-tt]) banded fp32 matrix (zeros elsewhere), so the
// inner loop is a boundary-free 64xRVx128 banded product; 1/sum folded into
// the epilogue. v tile staged as raw bf16.
// MODE 0: write x (fp32) to x0w.  MODE 1: blend with x0r via softmax(sw),
// write bf16 to xbw.
// ---------------------------------------------------------------------------
template <int CS, int MODE>
__global__ __launch_bounds__(256, 2) void attn_apply(
    const float* __restrict__ logits, int LP,
    const u16* __restrict__ vbf,
    const float* __restrict__ x0r, float* __restrict__ x0w,
    u16* __restrict__ xbw, const float* __restrict__ swp) {
  constexpr int HALF = (CS - 1) / 2;
  constexpr int SPAN = ((CS + 3) + 3) & ~3;  // 36 / 64
  constexpr int RV = 64 + SPAN;              // 100 / 128
  constexpr int VLD = 136;                   // ushort stride, 16B-aligned rows
  __shared__ __align__(16) u16 vl[RV * VLD];
  __shared__ __align__(16) float es[64 * RV];
  __shared__ float qsum[64 * 4];
  __shared__ float invsum[64];

  const int tid = threadIdx.x;
  const int t0 = blockIdx.x * 64;
  const int h = blockIdx.y;
  const int b = blockIdx.z;
  const int m0 = b * 2048 + t0;

  // Phase A: zero es, stage v window (bf16, zero-padded)
  for (int i = tid; i < 64 * RV / 4; i += 256)
    ((floatx4*)es)[i] = (floatx4){0.f, 0.f, 0.f, 0.f};
  for (int idx = tid; idx < RV * 16; idx += 256) {
    int r = idx >> 4, d8 = (idx & 15) * 8;
    int t = t0 + r - HALF;
    uint4 u = make_uint4(0u, 0u, 0u, 0u);
    if (r < 64 + CS - 1 && t >= 0 && t < 2048)
      u = *(const uint4*)&vbf[((size_t)(b * 2048 + t)) * 512 + h * 128 + d8];
    *(uint4*)&vl[r * VLD + d8] = u;
  }
  __syncthreads();

  // Phase B: exp + partial row sums (4 threads per row)
  {
    int tt = tid >> 2, qq = tid & 3;
    float ps = 0.f;
    const float* lrow = logits + (size_t)(m0 + tt) * LP + h * CS;
    for (int c = qq; c < CS; c += 4) {
      float ev = __expf(lrow[c]);
      es[tt * RV + tt + c] = ev;
      ps += ev;
    }
    qsum[tt * 4 + qq] = ps;
  }
  __syncthreads();
  if (tid < 64)
    invsum[tid] = 1.f / (qsum[tid * 4] + qsum[tid * 4 + 1] + qsum[tid * 4 + 2] + qsum[tid * 4 + 3]);
  __syncthreads();

  float sw0 = 0.5f, sw1 = 0.5f;
  if (MODE == 1) {
    float a0 = swp[0], a1 = swp[1];
    float mx = fmaxf(a0, a1);
    float e0 = __expf(a0 - mx), e1 = __expf(a1 - mx);
    float inv = 1.f / (e0 + e1);
    sw0 = e0 * inv;
    sw1 = e1 * inv;
  }

  // Phase D: register-tiled 4(t) x 4(d) banded product
  const int dg = tid & 31, rg = tid >> 5;
#pragma unroll
  for (int cell = 0; cell < 2; ++cell) {
    int tt0 = (rg + cell * 8) * 4;
    floatx4 acc[4];
#pragma unroll
    for (int i = 0; i < 4; ++i) acc[i] = (floatx4){0.f, 0.f, 0.f, 0.f};
    for (int rb = 0; rb < SPAN; rb += 4) {
      int r = tt0 + rb;
      floatx4 vr[4];
#pragma unroll
      for (int j = 0; j < 4; ++j) {
        uint2 u = *(const uint2*)&vl[(r + j) * VLD + dg * 4];
        vr[j] = (floatx4){bflo(u.x), bfhi(u.x), bflo(u.y), bfhi(u.y)};
      }
#pragma unroll
      for (int i = 0; i < 4; ++i) {
        floatx4 ev = *(const floatx4*)&es[(tt0 + i) * RV + r];
        acc[i] += vr[0] * ev.x;
        acc[i] += vr[1] * ev.y;
        acc[i] += vr[2] * ev.z;
        acc[i] += vr[3] * ev.w;
      }
    }
#pragma unroll
    for (int i = 0; i < 4; ++i) {
      int tt = tt0 + i;
      floatx4 xv = acc[i] * invsum[tt];
      size_t off = (size_t)(m0 + tt) * 512 + (size_t)(h * 128 + dg * 4);
      if (MODE == 0) {
        *(floatx4*)&x0w[off] = xv;
      } else {
        floatx4 pv = *(const floatx4*)&x0r[off];
        floatx4 o = pv * sw0 + xv * sw1;
        unsigned p0 = (unsigned)f2bf(o.x) | ((unsigned)f2bf(o.y) << 16);
        unsigned p1 = (unsigned)f2bf(o.z) | ((unsigned)f2bf(o.w) << 16);
        *(uint2*)&xbw[off] = make_uint2(p0, p1);
      }
    }
  }
}

// ---------------------------------------------------------------------------
extern "C" void kernel_launch(void* const* d_in, const int* in_sizes, int n_in,
                              void* d_out, int out_size, void* d_ws, size_t ws_size,
                              hipStream_t stream) {
  const float* q   = (const float*)d_in[0];
  // d_in[1] = key (unused by reference)
  const float* v   = (const float*)d_in[2];
  const float* w10 = (const float*)d_in[3];
  const float* w11 = (const float*)d_in[4];
  const float* w20 = (const float*)d_in[5];
  const float* w21 = (const float*)d_in[6];
  const float* w30 = (const float*)d_in[7];
  const float* w31 = (const float*)d_in[8];
  const float* sw  = (const float*)d_in[9];
  const float* wo  = (const float*)d_in[10];
  float* out = (float*)d_out;

  u16* base = (u16*)d_ws;
  u16* qb   = base;
  u16* vb   = base + 4194304;
  u16* w1b0 = base + 8388608;
  u16* w1b1 = base + 8650752;
  u16* w3b0 = base + 8912896;
  u16* w3b1 = base + 9175040;
  u16* wob  = base + 9437184;
  u16* w2b0 = base + 9699328;
  u16* w2b1 = base + 9764864;
  char* fb = (char*)d_ws + 19791872;  // 16B aligned
  float* logits0 = (float*)fb;               // 8192*128
  float* logits1 = logits0 + 1048576;        // 8192*256
  float* x0      = logits1 + 2097152;        // 8192*512 fp32
  u16* rq0 = (u16*)(x0 + 4194304);
  u16* rq1 = rq0 + 4194304;
  u16* v0b = rq1 + 4194304;
  u16* v1b = v0b + 4194304;
  u16* xb  = v1b + 4194304;
  // total ws use: 91,095,040 bytes

  convert_all<<<dim3(9664), dim3(256), 0, stream>>>(q, v, w10, w11, w30, w31, wo, w20, w21, base);

  dim3 blk(256);
  dim3 g512(64, 4), g128(64, 1), g256(64, 2);
  gemm_bt<1, 1><<<g512, blk, 0, stream>>>(qb, w1b0, nullptr, rq0, 512);
  gemm_bt<1, 1><<<g512, blk, 0, stream>>>(qb, w1b1, nullptr, rq1, 512);
  gemm_bt<1, 0><<<g512, blk, 0, stream>>>(vb, w3b0, nullptr, v0b, 512);
  gemm_bt<1, 0><<<g512, blk, 0, stream>>>(vb, w3b1, nullptr, v1b, 512);
  gemm_bt<0, 0><<<g128, blk, 0, stream>>>(rq0, w2b0, logits0, nullptr, 128);
  gemm_bt<0, 0><<<g256, blk, 0, stream>>>(rq1, w2b1, logits1, nullptr, 256);

  dim3 ga(32, 4, 4);
  attn_apply<31, 0><<<ga, blk, 0, stream>>>(logits0, 128, v0b, nullptr, x0, nullptr, nullptr);
  attn_apply<61, 1><<<ga, blk, 0, stream>>>(logits1, 256, v1b, x0, nullptr, xb, sw);

  gemm_bt<0, 0><<<g512, blk, 0, stream>>>(xb, wob, out, nullptr, 512);
}

// Round 2
// 183.228 us; speedup vs baseline: 1.2473x; 1.2473x over previous
//
#include <hip/hip_runtime.h>

typedef unsigned short u16;
typedef unsigned long long u64;
typedef float floatx4 __attribute__((ext_vector_type(4)));
typedef short shortx8 __attribute__((ext_vector_type(8)));

__device__ inline u16 f2bf(float f) {
  unsigned u = __float_as_uint(f);
  u += 0x7fffu + ((u >> 16) & 1u);
  return (u16)(u >> 16);
}
__device__ inline float bflo(unsigned u) { return __uint_as_float(u << 16); }
__device__ inline float bfhi(unsigned u) { return __uint_as_float(u & 0xffff0000u); }

// async global->LDS, 16B per lane. LDS dest is wave-uniform base + lane*16
// (m104/m108): pass the uniform segment base; layout must be lane-contiguous.
__device__ __forceinline__ void gl16(const u16* g, const u16* l) {
  __builtin_amdgcn_global_load_lds(
      (const __attribute__((address_space(1))) unsigned int*)(u64)(const void*)g,
      (__attribute__((address_space(3))) unsigned int*)(unsigned)(u64)(const void*)l,
      16, 0, 0);
}

// ---------------------------------------------------------------------------
// fp32 -> bf16 conversion of all tensors (w2_* zero-padded to 128/256 rows).
// ushort offsets in ws: qb 0 | vb 4194304 | w1cat 8388608 (1024x512: w1_0;w1_1)
// | w3cat 8912896 | wob 9437184 | w2b0p 9699328 (128x512) | w2b1p 9764864
// (256x512) | end 9895936
// ---------------------------------------------------------------------------
__global__ __launch_bounds__(256) void convert_all(
    const float* __restrict__ q, const float* __restrict__ v,
    const float* __restrict__ w10, const float* __restrict__ w11,
    const float* __restrict__ w30, const float* __restrict__ w31,
    const float* __restrict__ wo, const float* __restrict__ w20,
    const float* __restrict__ w21, u16* __restrict__ base) {
  size_t e = ((size_t)blockIdx.x * 256 + threadIdx.x) * 4;
  const float* src;
  u16* dst;
  size_t le;
  unsigned prows;
  if (e < 4194304ull)      { src = q;   dst = base;            le = e;            prows = 0x7fffffffu; }
  else if (e < 8388608ull) { src = v;   dst = base + 4194304;  le = e - 4194304;  prows = 0x7fffffffu; }
  else if (e < 8650752ull) { src = w10; dst = base + 8388608;  le = e - 8388608;  prows = 0x7fffffffu; }
  else if (e < 8912896ull) { src = w11; dst = base + 8650752;  le = e - 8650752;  prows = 0x7fffffffu; }
  else if (e < 9175040ull) { src = w30; dst = base + 8912896;  le = e - 8912896;  prows = 0x7fffffffu; }
  else if (e < 9437184ull) { src = w31; dst = base + 9175040;  le = e - 9175040;  prows = 0x7fffffffu; }
  else if (e < 9699328ull) { src = wo;  dst = base + 9437184;  le = e - 9437184;  prows = 0x7fffffffu; }
  else if (e < 9764864ull) { src = w20; dst = base + 9699328;  le = e - 9699328;  prows = 124; }
  else                     { src = w21; dst = base + 9764864;  le = e - 9764864;  prows = 244; }
  float4 val = make_float4(0.f, 0.f, 0.f, 0.f);
  if ((unsigned)(le >> 9) < prows) val = *(const float4*)(src + le);
  unsigned p0 = (unsigned)f2bf(val.x) | ((unsigned)f2bf(val.y) << 16);
  unsigned p1 = (unsigned)f2bf(val.z) | ((unsigned)f2bf(val.w) << 16);
  *(uint2*)(dst + le) = make_uint2(p0, p1);
}

// ---------------------------------------------------------------------------
// m97-structure GEMM core: C[m,n] = sum_k A[m,k]*W[n,k], K=512 fixed.
// 128x128 tile, BK=32, 4 waves 2x2 of 64x64, mfma_f32_16x16x32_bf16.
// global_load_lds width=16 staging into unpadded [128][32] LDS (layout is
// forced lane-contiguous by the HW). A/W/C passed pre-offset to the tile.
// ---------------------------------------------------------------------------
template <int OUTBF>
__device__ __forceinline__ void gemm_core(
    const u16* __restrict__ A, int lda, const u16* __restrict__ W, int ldw,
    float* __restrict__ Cf, u16* __restrict__ Cb, int ldc, int relu,
    u16* lA, u16* lB) {
  const int tid = threadIdx.x;
  const int wave = tid >> 6, lane = tid & 63;
  const int wm = (wave >> 1) * 64, wn = (wave & 1) * 64;
  const int lr = lane & 15, kq = (lane >> 4) * 8;
  const int sr = lane >> 2, sc = (lane & 3) * 8;

  floatx4 acc[4][4];
#pragma unroll
  for (int i = 0; i < 4; ++i)
#pragma unroll
    for (int j = 0; j < 4; ++j) acc[i][j] = (floatx4){0.f, 0.f, 0.f, 0.f};

  const u16* ga0 = A + (u64)(wave * 32 + sr) * lda + sc;
  const u16* ga1 = A + (u64)(wave * 32 + 16 + sr) * lda + sc;
  const u16* gb0 = W + (u64)(wave * 32 + sr) * ldw + sc;
  const u16* gb1 = W + (u64)(wave * 32 + 16 + sr) * ldw + sc;
  u16* la0 = lA + (wave * 32) * 32;
  u16* la1 = lA + (wave * 32 + 16) * 32;
  u16* lb0 = lB + (wave * 32) * 32;
  u16* lb1 = lB + (wave * 32 + 16) * 32;

  for (int k0 = 0; k0 < 512; k0 += 32) {
    __syncthreads();
    gl16(ga0 + k0, la0);
    gl16(ga1 + k0, la1);
    gl16(gb0 + k0, lb0);
    gl16(gb1 + k0, lb1);
    __syncthreads();
    shortx8 af[4], bf8[4];
#pragma unroll
    for (int i = 0; i < 4; ++i) {
      af[i] = *(const shortx8*)&lA[(wm + i * 16 + lr) * 32 + kq];
      bf8[i] = *(const shortx8*)&lB[(wn + i * 16 + lr) * 32 + kq];
    }
#pragma unroll
    for (int mi = 0; mi < 4; ++mi)
#pragma unroll
      for (int ni = 0; ni < 4; ++ni)
        acc[mi][ni] = __builtin_amdgcn_mfma_f32_16x16x32_bf16(af[mi], bf8[ni], acc[mi][ni], 0, 0, 0);
  }
  // C/D layout: col = lane&15, row = (lane>>4)*4 + r (m89/m91)
  const int er = wm + (lane >> 4) * 4;
  const int ec = wn + lr;
#pragma unroll
  for (int mi = 0; mi < 4; ++mi)
#pragma unroll
    for (int ni = 0; ni < 4; ++ni)
#pragma unroll
      for (int r = 0; r < 4; ++r) {
        float vv = acc[mi][ni][r];
        if (relu) vv = fmaxf(vv, 0.f);
        u64 off = (u64)(er + mi * 16 + r) * (u64)ldc + (u64)(ec + ni * 16);
        if (OUTBF) Cb[off] = f2bf(vv);
        else Cf[off] = vv;
      }
}

// fused q/v projection: grid (128, 8). x<64 -> q-half (relu), else v-half.
__global__ __launch_bounds__(256, 2) void k_qv(
    const u16* __restrict__ qb, const u16* __restrict__ vb,
    const u16* __restrict__ w1, const u16* __restrict__ w3,
    u16* __restrict__ rq, u16* __restrict__ vc) {
  __shared__ __align__(16) u16 lA[128 * 32];
  __shared__ __align__(16) u16 lB[128 * 32];
  const int bx = blockIdx.x, bn = blockIdx.y * 128;
  const bool isq = bx < 64;
  const int am = (isq ? bx : bx - 64) * 128;
  const u16* A = (isq ? qb : vb) + (u64)am * 512;
  const u16* W = (isq ? w1 : w3) + (u64)bn * 512;
  u16* Cb = (isq ? rq : vc) + (u64)am * 1024 + bn;
  gemm_core<1>(A, 512, W, 512, nullptr, Cb, 1024, isq ? 1 : 0, lA, lB);
}

// fused logits for both scales: grid (64, 3). y=0: scale0 (w2b0, rq cols 0..511),
// y=1,2: scale1 halves (w2b1, rq cols 512..1023). out [8192][384] fp32.
__global__ __launch_bounds__(256, 2) void k_logits(
    const u16* __restrict__ rq, const u16* __restrict__ w20,
    const u16* __restrict__ w21, float* __restrict__ lg) {
  __shared__ __align__(16) u16 lA[128 * 32];
  __shared__ __align__(16) u16 lB[128 * 32];
  const int am = blockIdx.x * 128;
  const int y = blockIdx.y;
  const u16* A = rq + (u64)am * 1024 + (y == 0 ? 0 : 512);
  const u16* W = (y == 0) ? w20 : (w21 + (u64)(y - 1) * 128 * 512);
  float* Cf = lg + (u64)am * 384 + y * 128;
  gemm_core<0>(A, 1024, W, 512, Cf, nullptr, 384, 0, lA, lB);
}

// final projection: grid (64, 4), fp32 out.
__global__ __launch_bounds__(256, 2) void k_final(
    const u16* __restrict__ xb, const u16* __restrict__ wo,
    float* __restrict__ out) {
  __shared__ __align__(16) u16 lA[128 * 32];
  __shared__ __align__(16) u16 lB[128 * 32];
  const int am = blockIdx.x * 128, bn = blockIdx.y * 128;
  gemm_core<0>(xb + (u64)am * 512, 512, wo + (u64)bn * 512, 512,
               out + (u64)am * 512 + bn, nullptr, 512, 0, lA, lB);
}

// ---------------------------------------------------------------------------
// Fused softmax + banded attn for one scale (unchanged numerics; vcat/logits
// are now strided concat buffers -> ldv / pre-offset base pointers).
// ---------------------------------------------------------------------------
template <int CS, int MODE>
__global__ __launch_bounds__(256, 2) void attn_apply(
    const float* __restrict__ logits, int LP,
    const u16* __restrict__ vbf, int ldv,
    const float* __restrict__ x0r, float* __restrict__ x0w,
    u16* __restrict__ xbw, const float* __restrict__ swp) {
  constexpr int HALF = (CS - 1) / 2;
  constexpr int SPAN = ((CS + 3) + 3) & ~3;  // 36 / 64
  constexpr int RV = 64 + SPAN;              // 100 / 128
  constexpr int VLD = 136;                   // ushort stride, 16B-aligned rows
  __shared__ __align__(16) u16 vl[RV * VLD];
  __shared__ __align__(16) float es[64 * RV];
  __shared__ float qsum[64 * 4];
  __shared__ float invsum[64];

  const int tid = threadIdx.x;
  const int t0 = blockIdx.x * 64;
  const int h = blockIdx.y;
  const int b = blockIdx.z;
  const int m0 = b * 2048 + t0;

  for (int i = tid; i < 64 * RV / 4; i += 256)
    ((floatx4*)es)[i] = (floatx4){0.f, 0.f, 0.f, 0.f};
  for (int idx = tid; idx < RV * 16; idx += 256) {
    int r = idx >> 4, d8 = (idx & 15) * 8;
    int t = t0 + r - HALF;
    uint4 u = make_uint4(0u, 0u, 0u, 0u);
    if (r < 64 + CS - 1 && t >= 0 && t < 2048)
      u = *(const uint4*)&vbf[(u64)(b * 2048 + t) * (u64)ldv + h * 128 + d8];
    *(uint4*)&vl[r * VLD + d8] = u;
  }
  __syncthreads();

  {
    int tt = tid >> 2, qq = tid & 3;
    float ps = 0.f;
    const float* lrow = logits + (u64)(m0 + tt) * LP + h * CS;
    for (int c = qq; c < CS; c += 4) {
      float ev = __expf(lrow[c]);
      es[tt * RV + tt + c] = ev;
      ps += ev;
    }
    qsum[tt * 4 + qq] = ps;
  }
  __syncthreads();
  if (tid < 64)
    invsum[tid] = 1.f / (qsum[tid * 4] + qsum[tid * 4 + 1] + qsum[tid * 4 + 2] + qsum[tid * 4 + 3]);
  __syncthreads();

  float sw0 = 0.5f, sw1 = 0.5f;
  if (MODE == 1) {
    float a0 = swp[0], a1 = swp[1];
    float mx = fmaxf(a0, a1);
    float e0 = __expf(a0 - mx), e1 = __expf(a1 - mx);
    float inv = 1.f / (e0 + e1);
    sw0 = e0 * inv;
    sw1 = e1 * inv;
  }

  const int dg = tid & 31, rg = tid >> 5;
#pragma unroll
  for (int cell = 0; cell < 2; ++cell) {
    int tt0 = (rg + cell * 8) * 4;
    floatx4 acc[4];
#pragma unroll
    for (int i = 0; i < 4; ++i) acc[i] = (floatx4){0.f, 0.f, 0.f, 0.f};
    for (int rb = 0; rb < SPAN; rb += 4) {
      int r = tt0 + rb;
      floatx4 vr[4];
#pragma unroll
      for (int j = 0; j < 4; ++j) {
        uint2 u = *(const uint2*)&vl[(r + j) * VLD + dg * 4];
        vr[j] = (floatx4){bflo(u.x), bfhi(u.x), bflo(u.y), bfhi(u.y)};
      }
#pragma unroll
      for (int i = 0; i < 4; ++i) {
        floatx4 ev = *(const floatx4*)&es[(tt0 + i) * RV + r];
        acc[i] += vr[0] * ev.x;
        acc[i] += vr[1] * ev.y;
        acc[i] += vr[2] * ev.z;
        acc[i] += vr[3] * ev.w;
      }
    }
#pragma unroll
    for (int i = 0; i < 4; ++i) {
      int tt = tt0 + i;
      floatx4 xv = acc[i] * invsum[tt];
      u64 off = (u64)(m0 + tt) * 512 + (u64)(h * 128 + dg * 4);
      if (MODE == 0) {
        *(floatx4*)&x0w[off] = xv;
      } else {
        floatx4 pv = *(const floatx4*)&x0r[off];
        floatx4 o = pv * sw0 + xv * sw1;
        unsigned p0 = (unsigned)f2bf(o.x) | ((unsigned)f2bf(o.y) << 16);
        unsigned p1 = (unsigned)f2bf(o.z) | ((unsigned)f2bf(o.w) << 16);
        *(uint2*)&xbw[off] = make_uint2(p0, p1);
      }
    }
  }
}

// ---------------------------------------------------------------------------
extern "C" void kernel_launch(void* const* d_in, const int* in_sizes, int n_in,
                              void* d_out, int out_size, void* d_ws, size_t ws_size,
                              hipStream_t stream) {
  const float* q   = (const float*)d_in[0];
  const float* v   = (const float*)d_in[2];
  const float* w10 = (const float*)d_in[3];
  const float* w11 = (const float*)d_in[4];
  const float* w20 = (const float*)d_in[5];
  const float* w21 = (const float*)d_in[6];
  const float* w30 = (const float*)d_in[7];
  const float* w31 = (const float*)d_in[8];
  const float* sw  = (const float*)d_in[9];
  const float* wo  = (const float*)d_in[10];
  float* out = (float*)d_out;

  u16* base  = (u16*)d_ws;
  u16* qb    = base;
  u16* vb    = base + 4194304;
  u16* w1cat = base + 8388608;
  u16* w3cat = base + 8912896;
  u16* wob   = base + 9437184;
  u16* w2b0  = base + 9699328;
  u16* w2b1  = base + 9764864;
  char* fb = (char*)d_ws + 19791872;
  float* logitsC = (float*)fb;            // [8192][384]
  float* x0      = logitsC + 3145728;     // [8192][512] fp32
  u16* rqcat = (u16*)(x0 + 4194304);      // [8192][1024] bf16
  u16* vcat  = rqcat + 8388608;           // [8192][1024] bf16
  u16* xb    = vcat + 8388608;            // [8192][512] bf16
  // total ws use: 91,095,040 bytes (same as round 1)

  convert_all<<<dim3(9664), dim3(256), 0, stream>>>(q, v, w10, w11, w30, w31, wo, w20, w21, base);

  dim3 blk(256);
  k_qv<<<dim3(128, 8), blk, 0, stream>>>(qb, vb, w1cat, w3cat, rqcat, vcat);
  k_logits<<<dim3(64, 3), blk, 0, stream>>>(rqcat, w2b0, w2b1, logitsC);

  dim3 ga(32, 4, 4);
  attn_apply<31, 0><<<ga, blk, 0, stream>>>(logitsC, 384, vcat, 1024, nullptr, x0, nullptr, nullptr);
  attn_apply<61, 1><<<ga, blk, 0, stream>>>(logitsC + 128, 384, vcat + 512, 1024, x0, nullptr, xb, sw);

  k_final<<<dim3(64, 4), blk, 0, stream>>>(xb, wob, out);
}